// Round 1
// baseline (330.409 us; speedup 1.0000x reference)
//
#include <hip/hip_runtime.h>
#include <hip/hip_bf16.h>
#include <stdint.h>

// JPEG decompress: dequant -> 8x8 IDCT -> merge -> 2x chroma upsample ->
// YCbCr->RGB -> clip/255.  Fully fused through LDS: one 256-thread block
// handles a 32(w) x 16(h) output tile = 8 Y blocks + 2 Cb + 2 Cr blocks.
//
// Memory-bound target: ~101 MB read + ~201 MB write -> ~48 us at 6.3 TB/s.

__device__ __forceinline__ float read_scalar_as_float(const void* p) {
    // Harness passes Python scalars as 1-elem arrays; dtype may be int32 or
    // float32. Disambiguate by exponent field: int 1/1024 has exp=0; plausible
    // float scalars (1.0, 1024.0) have exp in [64,191].
    unsigned bits = *(const unsigned*)p;
    unsigned e = (bits >> 23) & 0xffu;
    if (e >= 64u && e <= 191u) return __uint_as_float(bits);
    return (float)(int)bits;
}

__global__ __launch_bounds__(256) void jpeg_decode_kernel(
    const float* __restrict__ gy,
    const float* __restrict__ gcb,
    const float* __restrict__ gcr,
    const void* __restrict__ p_h,
    const void* __restrict__ p_w,
    const void* __restrict__ p_f,
    const float* __restrict__ y_table,
    const float* __restrict__ c_table,
    const float* __restrict__ alpha,
    const float* __restrict__ idct_t,
    const float* __restrict__ cmat,
    const float* __restrict__ shift,
    float* __restrict__ out,
    int y_size)
{
    __shared__ float sCoef[768];   // 12 blocks x 64 dequantized coefs
    __shared__ float sTmp[768];    // row-pass intermediate
    __shared__ float sM[64];       // M[u*8+x] = cos((2x+1)u pi/16)
    __shared__ float sY[512];      // 16 x 32 luma tile
    __shared__ float sCb[128];     // 8 x 16 chroma tile
    __shared__ float sCr[128];

    const int H = (int)read_scalar_as_float(p_h);
    const int W = (int)read_scalar_as_float(p_w);
    const float f = read_scalar_as_float(p_f);

    const int HW = H * W;
    const int B = y_size / HW;
    const int tiles_x = W >> 5;            // 32-wide tiles
    const int tiles_y = H >> 4;            // 16-tall tiles
    const int tiles_per_img = tiles_x * tiles_y;
    const int n_tiles = B * tiles_per_img;

    const int tid = threadIdx.x;

    for (int tile = blockIdx.x; tile < n_tiles; tile += gridDim.x) {
        const int b  = tile / tiles_per_img;
        const int r  = tile - b * tiles_per_img;
        const int ty = r / tiles_x;
        const int tx = r - ty * tiles_x;

        // ---- Phase 0: stage + dequant 12 blocks into LDS ----
        if (tid < 64) {
            // M[u,x] = idct_t[u,0,x,0]; flat idx u*512 + x*8
            sM[tid] = idct_t[(tid >> 3) * 512 + (tid & 7) * 8];
        }
        const int wb = W >> 3;   // luma blocks per row
        #pragma unroll
        for (int i = 0; i < 3; ++i) {
            const int t   = tid + i * 256;
            const int blk = t >> 6;
            const int p   = t & 63;
            float v;
            if (blk < 8) {
                const int by = blk >> 2, bx = blk & 3;
                const int n  = (ty * 2 + by) * wb + (tx * 4 + bx);
                v = gy[((size_t)b * (HW >> 6) + n) * 64 + p]
                    * (y_table[p] * f) * alpha[p];
            } else {
                const int k = (blk - 8) & 1;
                const int n = ty * (W >> 4) + tx * 2 + k;
                const float* src = (blk < 10) ? gcb : gcr;
                v = src[((size_t)b * (HW >> 8) + n) * 64 + p]
                    * (c_table[p] * f) * alpha[p];
            }
            sCoef[t] = v;
        }
        __syncthreads();

        // ---- Phase 1: row pass  tmp[u,y] = sum_v coef[u,v] * M[v,y] ----
        #pragma unroll
        for (int i = 0; i < 3; ++i) {
            const int t  = tid + i * 256;
            const int yy = t & 7;
            const int cbase = t & ~7;     // blk*64 + u*8
            float acc = 0.f;
            #pragma unroll
            for (int v = 0; v < 8; ++v)
                acc += sCoef[cbase + v] * sM[v * 8 + yy];
            sTmp[t] = acc;
        }
        __syncthreads();

        // ---- Phase 2: col pass  out[x,y] = 0.25*sum_u M[u,x]*tmp[u,y] + 128
        #pragma unroll
        for (int i = 0; i < 3; ++i) {
            const int t   = tid + i * 256;
            const int blk = t >> 6;
            const int p   = t & 63;
            const int x   = p >> 3;
            const int yy  = p & 7;
            const int tbase = (t & ~63);
            float acc = 0.f;
            #pragma unroll
            for (int u = 0; u < 8; ++u)
                acc += sM[u * 8 + x] * sTmp[tbase + u * 8 + yy];
            const float val = 0.25f * acc + 128.0f;
            if (blk < 8) {
                const int by = blk >> 2, bx = blk & 3;
                sY[(by * 8 + x) * 32 + bx * 8 + yy] = val;
            } else if (blk < 10) {
                sCb[x * 16 + (blk - 8) * 8 + yy] = val;
            } else {
                sCr[x * 16 + (blk - 10) * 8 + yy] = val;
            }
        }

        // uniform small loads (L1-resident)
        const float m00 = cmat[0], m01 = cmat[1], m02 = cmat[2];
        const float m10 = cmat[3], m11 = cmat[4], m12 = cmat[5];
        const float m20 = cmat[6], m21 = cmat[7], m22 = cmat[8];
        const float s0 = shift[0], s1 = shift[1], s2 = shift[2];
        __syncthreads();

        // ---- Phase 3: upsample + color convert + write [B,3,H,W] ----
        const size_t obase = (size_t)b * 3 * HW;
        const int row0 = ty * 16;
        const int col0 = tx * 32;
        #pragma unroll
        for (int i = 0; i < 2; ++i) {
            const int q  = tid + i * 256;
            const int py = q >> 5;
            const int px = q & 31;
            const float yv = sY[py * 32 + px] + s0;
            const int ci = (py >> 1) * 16 + (px >> 1);
            const float cbv = sCb[ci] + s1;
            const float crv = sCr[ci] + s2;
            float rr = yv * m00 + cbv * m10 + crv * m20;
            float gg = yv * m01 + cbv * m11 + crv * m21;
            float bb = yv * m02 + cbv * m12 + crv * m22;
            rr = fminf(fmaxf(rr, 0.f), 255.f) * (1.0f / 255.0f);
            gg = fminf(fmaxf(gg, 0.f), 255.f) * (1.0f / 255.0f);
            bb = fminf(fmaxf(bb, 0.f), 255.f) * (1.0f / 255.0f);
            const size_t pix = (size_t)(row0 + py) * W + (col0 + px);
            out[obase + pix]            = rr;
            out[obase + (size_t)HW + pix]   = gg;
            out[obase + 2 * (size_t)HW + pix] = bb;
        }
        __syncthreads();   // protect LDS before next tile's staging
    }
}

extern "C" void kernel_launch(void* const* d_in, const int* in_sizes, int n_in,
                              void* d_out, int out_size, void* d_ws, size_t ws_size,
                              hipStream_t stream) {
    const float* gy   = (const float*)d_in[0];
    const float* gcb  = (const float*)d_in[1];
    const float* gcr  = (const float*)d_in[2];
    const void*  p_h  = d_in[3];
    const void*  p_w  = d_in[4];
    const void*  p_f  = d_in[5];
    const float* y_t  = (const float*)d_in[6];
    const float* c_t  = (const float*)d_in[7];
    const float* al   = (const float*)d_in[8];
    const float* idct = (const float*)d_in[9];
    const float* mat  = (const float*)d_in[10];
    const float* shf  = (const float*)d_in[11];
    float* out = (float*)d_out;

    // each tile produces 32*16 px * 3 channels = 1536 output floats
    int n_tiles = out_size / 1536;
    if (n_tiles < 1) n_tiles = 1;

    jpeg_decode_kernel<<<dim3(n_tiles), dim3(256), 0, stream>>>(
        gy, gcb, gcr, p_h, p_w, p_f, y_t, c_t, al, idct, mat, shf,
        out, in_sizes[0]);
}

// Round 2
// 293.856 us; speedup vs baseline: 1.1244x; 1.1244x over previous
//
#include <hip/hip_runtime.h>
#include <hip/hip_bf16.h>
#include <stdint.h>

// JPEG decompress: dequant -> 8x8 IDCT -> merge -> 2x chroma upsample ->
// YCbCr->RGB -> clip/255.  Fully fused through LDS.
// One 256-thread block = one 32x32 pixel tile = 16 Y + 4 Cb + 4 Cr blocks.
// All global traffic is dwordx4 (16 B/lane, 1 KB/wave contiguous).
// Memory-bound target: ~101 MB read + ~201 MB write -> ~48 us at 6.3 TB/s.

__device__ __forceinline__ float read_scalar_as_float(const void* p) {
    // Python scalars arrive as 1-elem arrays, dtype int32 or float32.
    // Disambiguate by exponent field: small ints have exp=0; plausible float
    // scalars (0.25..1e19) have exp in [64,191].
    unsigned bits = *(const unsigned*)p;
    unsigned e = (bits >> 23) & 0xffu;
    if (e >= 64u && e <= 191u) return __uint_as_float(bits);
    return (float)(int)bits;
}

__global__ __launch_bounds__(256) void jpeg_decode_kernel(
    const float* __restrict__ gy,
    const float* __restrict__ gcb,
    const float* __restrict__ gcr,
    const void* __restrict__ p_h,
    const void* __restrict__ p_w,
    const void* __restrict__ p_f,
    const float* __restrict__ y_table,
    const float* __restrict__ c_table,
    const float* __restrict__ alpha,
    const float* __restrict__ idct_t,
    const float* __restrict__ cmat,
    const float* __restrict__ shift,
    float* __restrict__ out,
    int y_size)
{
    __shared__ float sQY[64];        // y_table * f * alpha
    __shared__ float sQC[64];        // c_table * f * alpha
    __shared__ float sM[64];         // M[v*8+y] = cos((2y+1)v pi/16)
    __shared__ float sCoef[1536];    // 24 blocks x 64 raw coefs
    __shared__ float sTmp[1536];     // row-pass, TRANSPOSED: [blk][y][u]
    __shared__ float sY[32 * 36];    // 32x32 luma tile, stride 36 (bank pad)
    __shared__ float sCb[16 * 20];   // 16x16 chroma, stride 20 (bank pad)
    __shared__ float sCr[16 * 20];

    const int H = (int)read_scalar_as_float(p_h);
    const int W = (int)read_scalar_as_float(p_w);
    const float f = read_scalar_as_float(p_f);

    const int HW = H * W;
    const int B = y_size / HW;
    const int tiles_x = W >> 5;            // 32x32 tiles
    const int tiles_y = H >> 5;
    const int tpi = tiles_x * tiles_y;
    const int n_tiles = B * tpi;

    const int tid = threadIdx.x;

    // ---- one-time: tables into LDS, color matrix into SGPRs ----
    if (tid < 64) {
        const float a = alpha[tid];
        sQY[tid] = y_table[tid] * f * a;
        sQC[tid] = c_table[tid] * f * a;
        sM[tid]  = idct_t[(tid >> 3) * 512 + (tid & 7) * 8];
    }
    const float m00 = cmat[0], m01 = cmat[1], m02 = cmat[2];
    const float m10 = cmat[3], m11 = cmat[4], m12 = cmat[5];
    const float m20 = cmat[6], m21 = cmat[7], m22 = cmat[8];
    const float s0 = shift[0], s1 = shift[1], s2 = shift[2];
    __syncthreads();

    for (int tile = blockIdx.x; tile < n_tiles; tile += gridDim.x) {
        const int b  = tile / tpi;
        const int r  = tile - b * tpi;
        const int ty = r / tiles_x;
        const int tx = r - ty * tiles_x;

        // ---- Phase 0: stage raw coefs, pure float4 copy ----
        {
            const int blk = tid >> 4;              // 0..15 (Y)
            const int p4  = (tid & 15) * 4;
            const int by = blk >> 2, bx = blk & 3;
            const int n  = (ty * 4 + by) * (W >> 3) + tx * 4 + bx;
            const float4 v = *(const float4*)(gy + ((size_t)b * (HW >> 6) + n) * 64 + p4);
            *(float4*)(sCoef + blk * 64 + p4) = v;
            if (tid < 128) {
                const int cblk = tid >> 4;         // 0..3 Cb, 4..7 Cr
                const int cp4  = (tid & 15) * 4;
                const int c  = cblk & 3;
                const int cy = c >> 1, cx = c & 1;
                const int cn = (ty * 2 + cy) * (W >> 4) + tx * 2 + cx;
                const float* src = (cblk < 4) ? gcb : gcr;
                const float4 cv = *(const float4*)(src + ((size_t)b * (HW >> 8) + cn) * 64 + cp4);
                *(float4*)(sCoef + 1024 + cblk * 64 + cp4) = cv;
            }
        }
        __syncthreads();

        // ---- Phase 1: dequant + row pass; write transposed tmp[blk][y][u] --
        {
            const int p  = tid & 63;
            const int u  = p >> 3;
            const int yy = p & 7;
            // premultiplied (dequant * basis) per v, for Y and chroma tables
            float pmy[8], pmc[8];
            #pragma unroll
            for (int v = 0; v < 8; ++v) {
                const float mv = sM[v * 8 + yy];
                pmy[v] = sQY[u * 8 + v] * mv;
                pmc[v] = sQC[u * 8 + v] * mv;
            }
            const int blk0 = tid >> 6;             // wave id: 0..3
            #pragma unroll
            for (int i = 0; i < 6; ++i) {
                const int blk = blk0 + i * 4;      // i<4: Y, i==4: Cb, i==5: Cr
                const float4 c0 = *(const float4*)(sCoef + blk * 64 + u * 8);
                const float4 c1 = *(const float4*)(sCoef + blk * 64 + u * 8 + 4);
                const float* pm = (i < 4) ? pmy : pmc;
                float acc = c0.x * pm[0] + c0.y * pm[1] + c0.z * pm[2] + c0.w * pm[3]
                          + c1.x * pm[4] + c1.y * pm[5] + c1.z * pm[6] + c1.w * pm[7];
                sTmp[blk * 64 + yy * 8 + u] = acc;   // transposed store
            }
        }
        __syncthreads();

        // ---- Phase 2: col pass, write Y/Cb/Cr pixel planes ----
        {
            const int p  = tid & 63;
            const int x  = p >> 3;
            const int yy = p & 7;
            float mu[8];
            #pragma unroll
            for (int u = 0; u < 8; ++u) mu[u] = sM[u * 8 + x];
            const int blk0 = tid >> 6;
            #pragma unroll
            for (int i = 0; i < 6; ++i) {
                const int blk = blk0 + i * 4;
                const float4 t0 = *(const float4*)(sTmp + blk * 64 + yy * 8);
                const float4 t1 = *(const float4*)(sTmp + blk * 64 + yy * 8 + 4);
                float acc = t0.x * mu[0] + t0.y * mu[1] + t0.z * mu[2] + t0.w * mu[3]
                          + t1.x * mu[4] + t1.y * mu[5] + t1.z * mu[6] + t1.w * mu[7];
                const float val = 0.25f * acc + 128.0f;
                if (i < 4) {
                    const int by = blk >> 2, bx = blk & 3;
                    sY[(by * 8 + x) * 36 + bx * 8 + yy] = val;
                } else if (i == 4) {
                    const int c = blk - 16;
                    sCb[((c >> 1) * 8 + x) * 20 + (c & 1) * 8 + yy] = val;
                } else {
                    const int c = blk - 20;
                    sCr[((c >> 1) * 8 + x) * 20 + (c & 1) * 8 + yy] = val;
                }
            }
        }
        __syncthreads();

        // ---- Phase 3: upsample + color convert + float4 stores [B,3,H,W] --
        {
            const int py  = tid >> 3;              // 0..31
            const int px  = (tid & 7) * 4;         // 0,4,...,28
            const float4 yv4 = *(const float4*)(sY + py * 36 + px);
            const int crow = (py >> 1) * 20;
            const int ccol = px >> 1;
            const float cb0 = sCb[crow + ccol]     + s1;
            const float cb1 = sCb[crow + ccol + 1] + s1;
            const float cr0 = sCr[crow + ccol]     + s2;
            const float cr1 = sCr[crow + ccol + 1] + s2;

            float yv[4] = { yv4.x + s0, yv4.y + s0, yv4.z + s0, yv4.w + s0 };
            float cbv[4] = { cb0, cb0, cb1, cb1 };
            float crv[4] = { cr0, cr0, cr1, cr1 };

            float4 Rv, Gv, Bv;
            float* rp = &Rv.x; float* gp = &Gv.x; float* bp = &Bv.x;
            #pragma unroll
            for (int j = 0; j < 4; ++j) {
                float rr = yv[j] * m00 + cbv[j] * m10 + crv[j] * m20;
                float gg = yv[j] * m01 + cbv[j] * m11 + crv[j] * m21;
                float bb = yv[j] * m02 + cbv[j] * m12 + crv[j] * m22;
                rp[j] = fminf(fmaxf(rr, 0.f), 255.f) * (1.0f / 255.0f);
                gp[j] = fminf(fmaxf(gg, 0.f), 255.f) * (1.0f / 255.0f);
                bp[j] = fminf(fmaxf(bb, 0.f), 255.f) * (1.0f / 255.0f);
            }

            const size_t obase = (size_t)b * 3 * HW;
            const size_t pix = (size_t)(ty * 32 + py) * W + (tx * 32 + px);
            *(float4*)(out + obase + pix)                    = Rv;
            *(float4*)(out + obase + (size_t)HW + pix)       = Gv;
            *(float4*)(out + obase + 2 * (size_t)HW + pix)   = Bv;
        }
        __syncthreads();   // protect LDS before next tile's staging
    }
}

extern "C" void kernel_launch(void* const* d_in, const int* in_sizes, int n_in,
                              void* d_out, int out_size, void* d_ws, size_t ws_size,
                              hipStream_t stream) {
    const float* gy   = (const float*)d_in[0];
    const float* gcb  = (const float*)d_in[1];
    const float* gcr  = (const float*)d_in[2];
    const void*  p_h  = d_in[3];
    const void*  p_w  = d_in[4];
    const void*  p_f  = d_in[5];
    const float* y_t  = (const float*)d_in[6];
    const float* c_t  = (const float*)d_in[7];
    const float* al   = (const float*)d_in[8];
    const float* idct = (const float*)d_in[9];
    const float* mat  = (const float*)d_in[10];
    const float* shf  = (const float*)d_in[11];
    float* out = (float*)d_out;

    // each tile produces 32*32 px * 3 channels = 3072 output floats
    int n_tiles = out_size / 3072;
    if (n_tiles < 1) n_tiles = 1;

    jpeg_decode_kernel<<<dim3(n_tiles), dim3(256), 0, stream>>>(
        gy, gcb, gcr, p_h, p_w, p_f, y_t, c_t, al, idct, mat, shf,
        out, in_sizes[0]);
}

// Round 3
// 284.725 us; speedup vs baseline: 1.1604x; 1.0321x over previous
//
#include <hip/hip_runtime.h>
#include <hip/hip_bf16.h>
#include <stdint.h>

// JPEG decompress: dequant -> 8x8 IDCT -> merge -> 2x chroma upsample ->
// YCbCr->RGB -> clip/255.  Fully fused through LDS.
// One 256-thread block = one 32x32 pixel tile = 16 Y + 4 Cb + 4 Cr blocks.
// All global traffic is dwordx4 (16 B/lane) with nontemporal hints (data is
// one-touch streamed; don't allocate in L2/L3).
// Memory-bound target: ~101 MB read + ~201 MB write -> ~48 us at 6.3 TB/s.

typedef float vfloat4 __attribute__((ext_vector_type(4)));

__device__ __forceinline__ float read_scalar_as_float(const void* p) {
    // Python scalars arrive as 1-elem arrays, dtype int32 or float32.
    // Disambiguate by exponent field: small ints have exp=0; plausible float
    // scalars have exp in [64,191].
    unsigned bits = *(const unsigned*)p;
    unsigned e = (bits >> 23) & 0xffu;
    if (e >= 64u && e <= 191u) return __uint_as_float(bits);
    return (float)(int)bits;
}

__global__ __launch_bounds__(256) void jpeg_decode_kernel(
    const float* __restrict__ gy,
    const float* __restrict__ gcb,
    const float* __restrict__ gcr,
    const void* __restrict__ p_h,
    const void* __restrict__ p_w,
    const void* __restrict__ p_f,
    const float* __restrict__ y_table,
    const float* __restrict__ c_table,
    const float* __restrict__ alpha,
    const float* __restrict__ idct_t,
    const float* __restrict__ cmat,
    const float* __restrict__ shift,
    float* __restrict__ out,
    int y_size)
{
    __shared__ float sQY[64];        // y_table * f * alpha
    __shared__ float sQC[64];        // c_table * f * alpha
    __shared__ float sM[64];         // sM[i*8+j] = cos((2j+1) i pi/16)
    __shared__ float sCoef[1536];    // 24 blocks x 64 raw coefs
    __shared__ float sTmp[1536];     // row-pass, TRANSPOSED: [blk][y][u]
    __shared__ float sY[32 * 36];    // 32x32 luma tile, stride 36 (bank pad)
    __shared__ float sCb[16 * 20];   // 16x16 chroma, stride 20 (bank pad)
    __shared__ float sCr[16 * 20];

    const int H = (int)read_scalar_as_float(p_h);
    const int W = (int)read_scalar_as_float(p_w);
    const float f = read_scalar_as_float(p_f);

    const int HW = H * W;
    const int B = y_size / HW;
    const int tiles_x = W >> 5;            // 32x32 tiles
    const int tiles_y = H >> 5;
    const int tpi = tiles_x * tiles_y;
    const int n_tiles = B * tpi;

    const int tid = threadIdx.x;

    // ---- one-time: tables into LDS, color matrix into SGPRs ----
    if (tid < 64) {
        const float a = alpha[tid];
        sQY[tid] = y_table[tid] * f * a;
        sQC[tid] = c_table[tid] * f * a;
        sM[tid]  = idct_t[(tid >> 3) * 512 + (tid & 7) * 8];
    }
    const float m00 = cmat[0], m01 = cmat[1], m02 = cmat[2];
    const float m10 = cmat[3], m11 = cmat[4], m12 = cmat[5];
    const float m20 = cmat[6], m21 = cmat[7], m22 = cmat[8];
    const float s0 = shift[0], s1 = shift[1], s2 = shift[2];
    __syncthreads();

    for (int tile = blockIdx.x; tile < n_tiles; tile += gridDim.x) {
        const int b  = tile / tpi;
        const int r  = tile - b * tpi;
        const int ty = r / tiles_x;
        const int tx = r - ty * tiles_x;

        // ---- Phase 0: stage raw coefs; both NT loads issued before any
        //      LDS store so the chroma load rides the Y load's vmcnt window.
        {
            const int blk = tid >> 4;              // 0..15 (Y)
            const int p4  = (tid & 15) * 4;
            const int by = blk >> 2, bx = blk & 3;
            const int n  = (ty * 4 + by) * (W >> 3) + tx * 4 + bx;
            const vfloat4 vy = __builtin_nontemporal_load(
                (const vfloat4*)(gy + ((size_t)b * (HW >> 6) + n) * 64 + p4));

            const bool have_c = (tid < 128);
            vfloat4 vc;
            int cblk = 0, cp4 = 0;
            if (have_c) {
                cblk = tid >> 4;                   // 0..3 Cb, 4..7 Cr
                cp4  = (tid & 15) * 4;
                const int c  = cblk & 3;
                const int cy = c >> 1, cx = c & 1;
                const int cn = (ty * 2 + cy) * (W >> 4) + tx * 2 + cx;
                const float* src = (cblk < 4) ? gcb : gcr;
                vc = __builtin_nontemporal_load(
                    (const vfloat4*)(src + ((size_t)b * (HW >> 8) + cn) * 64 + cp4));
            }
            *(vfloat4*)(sCoef + blk * 64 + p4) = vy;
            if (have_c)
                *(vfloat4*)(sCoef + 1024 + cblk * 64 + cp4) = vc;
        }
        __syncthreads();

        // ---- Phase 1: dequant + row pass; write transposed tmp[blk][y][u] --
        {
            const int p  = tid & 63;
            const int u  = p >> 3;
            const int yy = p & 7;
            // premultiplied (dequant * basis) per v, for Y and chroma tables
            float pmy[8], pmc[8];
            #pragma unroll
            for (int v = 0; v < 8; ++v) {
                const float mv = sM[v * 8 + yy];
                pmy[v] = sQY[u * 8 + v] * mv;
                pmc[v] = sQC[u * 8 + v] * mv;
            }
            const int blk0 = tid >> 6;             // wave id: 0..3
            #pragma unroll
            for (int i = 0; i < 6; ++i) {
                const int blk = blk0 + i * 4;      // i<4: Y, i==4: Cb, i==5: Cr
                const float4 c0 = *(const float4*)(sCoef + blk * 64 + u * 8);
                const float4 c1 = *(const float4*)(sCoef + blk * 64 + u * 8 + 4);
                const float* pm = (i < 4) ? pmy : pmc;
                float acc = c0.x * pm[0] + c0.y * pm[1] + c0.z * pm[2] + c0.w * pm[3]
                          + c1.x * pm[4] + c1.y * pm[5] + c1.z * pm[6] + c1.w * pm[7];
                sTmp[blk * 64 + yy * 8 + u] = acc;   // transposed store
            }
        }
        __syncthreads();

        // ---- Phase 2: col pass, write Y/Cb/Cr pixel planes ----
        {
            const int p  = tid & 63;
            const int x  = p >> 3;
            const int yy = p & 7;
            float mu[8];
            #pragma unroll
            for (int u = 0; u < 8; ++u) mu[u] = sM[u * 8 + x];
            const int blk0 = tid >> 6;
            #pragma unroll
            for (int i = 0; i < 6; ++i) {
                const int blk = blk0 + i * 4;
                const float4 t0 = *(const float4*)(sTmp + blk * 64 + yy * 8);
                const float4 t1 = *(const float4*)(sTmp + blk * 64 + yy * 8 + 4);
                float acc = t0.x * mu[0] + t0.y * mu[1] + t0.z * mu[2] + t0.w * mu[3]
                          + t1.x * mu[4] + t1.y * mu[5] + t1.z * mu[6] + t1.w * mu[7];
                const float val = 0.25f * acc + 128.0f;
                if (i < 4) {
                    const int by = blk >> 2, bx = blk & 3;
                    sY[(by * 8 + x) * 36 + bx * 8 + yy] = val;
                } else if (i == 4) {
                    const int c = blk - 16;
                    sCb[((c >> 1) * 8 + x) * 20 + (c & 1) * 8 + yy] = val;
                } else {
                    const int c = blk - 20;
                    sCr[((c >> 1) * 8 + x) * 20 + (c & 1) * 8 + yy] = val;
                }
            }
        }
        __syncthreads();

        // ---- Phase 3: upsample + color convert + NT float4 stores ----
        {
            const int py  = tid >> 3;              // 0..31
            const int px  = (tid & 7) * 4;         // 0,4,...,28
            const float4 yv4 = *(const float4*)(sY + py * 36 + px);
            const int crow = (py >> 1) * 20;
            const int ccol = px >> 1;
            const float cb0 = sCb[crow + ccol]     + s1;
            const float cb1 = sCb[crow + ccol + 1] + s1;
            const float cr0 = sCr[crow + ccol]     + s2;
            const float cr1 = sCr[crow + ccol + 1] + s2;

            float yv[4] = { yv4.x + s0, yv4.y + s0, yv4.z + s0, yv4.w + s0 };
            float cbv[4] = { cb0, cb0, cb1, cb1 };
            float crv[4] = { cr0, cr0, cr1, cr1 };

            vfloat4 Rv, Gv, Bv;
            #pragma unroll
            for (int j = 0; j < 4; ++j) {
                float rr = yv[j] * m00 + cbv[j] * m10 + crv[j] * m20;
                float gg = yv[j] * m01 + cbv[j] * m11 + crv[j] * m21;
                float bb = yv[j] * m02 + cbv[j] * m12 + crv[j] * m22;
                Rv[j] = fminf(fmaxf(rr, 0.f), 255.f) * (1.0f / 255.0f);
                Gv[j] = fminf(fmaxf(gg, 0.f), 255.f) * (1.0f / 255.0f);
                Bv[j] = fminf(fmaxf(bb, 0.f), 255.f) * (1.0f / 255.0f);
            }

            const size_t obase = (size_t)b * 3 * HW;
            const size_t pix = (size_t)(ty * 32 + py) * W + (tx * 32 + px);
            __builtin_nontemporal_store(Rv, (vfloat4*)(out + obase + pix));
            __builtin_nontemporal_store(Gv, (vfloat4*)(out + obase + (size_t)HW + pix));
            __builtin_nontemporal_store(Bv, (vfloat4*)(out + obase + 2 * (size_t)HW + pix));
        }
        __syncthreads();   // protect LDS before next tile's staging
    }
}

extern "C" void kernel_launch(void* const* d_in, const int* in_sizes, int n_in,
                              void* d_out, int out_size, void* d_ws, size_t ws_size,
                              hipStream_t stream) {
    const float* gy   = (const float*)d_in[0];
    const float* gcb  = (const float*)d_in[1];
    const float* gcr  = (const float*)d_in[2];
    const void*  p_h  = d_in[3];
    const void*  p_w  = d_in[4];
    const void*  p_f  = d_in[5];
    const float* y_t  = (const float*)d_in[6];
    const float* c_t  = (const float*)d_in[7];
    const float* al   = (const float*)d_in[8];
    const float* idct = (const float*)d_in[9];
    const float* mat  = (const float*)d_in[10];
    const float* shf  = (const float*)d_in[11];
    float* out = (float*)d_out;

    // each tile produces 32*32 px * 3 channels = 3072 output floats
    int n_tiles = out_size / 3072;
    if (n_tiles < 1) n_tiles = 1;

    jpeg_decode_kernel<<<dim3(n_tiles), dim3(256), 0, stream>>>(
        gy, gcb, gcr, p_h, p_w, p_f, y_t, c_t, al, idct, mat, shf,
        out, in_sizes[0]);
}